// Round 1
// baseline (813.590 us; speedup 1.0000x reference)
//
#include <hip/hip_runtime.h>
#include <hip/hip_bf16.h>

typedef __attribute__((ext_vector_type(8))) short short8;
typedef __attribute__((ext_vector_type(4))) float floatx4;

#define D_DIM 256
#define K_DIM 768
#define BM 64      // M rows per block
#define BK 32      // k-slice per step
#define PAD 40     // LDS row stride in shorts: 80B = 20 banks; free at 16-lane granularity
#define NSTEP 24   // K_DIM / BK

// fp32 -> bf16 round-to-nearest-even (no NaN path needed: Gaussian inputs)
__device__ __forceinline__ short f2bf(float x) {
    union { float f; unsigned u; } a; a.f = x;
    unsigned r = a.u + 0x7fffu + ((a.u >> 16) & 1u);
    return (short)(r >> 16);
}

// W [K_DIM][D_DIM] fp32 -> Wt [D_DIM][K_DIM] bf16 (transpose + convert), 32x32 LDS tiles
__global__ __launch_bounds__(256) void wt_kernel(const float* __restrict__ W,
                                                 short* __restrict__ Wt) {
    __shared__ float tile[32][33];
    const int k0 = blockIdx.x * 32, n0 = blockIdx.y * 32;
    const int tx = threadIdx.x & 31, ty = threadIdx.x >> 5;  // ty 0..7
#pragma unroll
    for (int i = 0; i < 32; i += 8)
        tile[ty + i][tx] = W[(size_t)(k0 + ty + i) * D_DIM + n0 + tx];
    __syncthreads();
#pragma unroll
    for (int i = 0; i < 32; i += 8)
        Wt[(size_t)(n0 + ty + i) * K_DIM + k0 + tx] = f2bf(tile[tx][ty + i]);
}

// Fused gather + GEMM + bias + relu.
// C tile 64x256 per block (full D in N -> A panel read ONCE).
// 4 waves side by side in N, each wave 64x64 via 4x4 mfma_f32_16x16x32_bf16.
// Pipeline: single-barrier LDS double-buffer; A prefetch 2-deep (HBM latency),
// B prefetch 1-deep (L2-hot Wt). Issue order B-then-A so the staging wait
// retires at vmcnt(2) and the 2-deep A loads stay in flight across s_barrier.
__global__ __launch_bounds__(256, 3) void edge_gemm(
    const float* __restrict__ edge, const float* __restrict__ node,
    const int* __restrict__ src, const int* __restrict__ tgt,
    const short* __restrict__ Wt, const float* __restrict__ bias,
    float* __restrict__ out, int E)
{
    __shared__ short As[2][BM][PAD];      // 10240 B
    __shared__ short Bs[2][D_DIM][PAD];   // 40960 B  (total 51.2 KB -> 3 blocks/CU)

    const int tid = threadIdx.x;
    const int m0 = blockIdx.x * BM;

    // ---- staging coords: 4 threads per A row, 8 floats each ----
    const int arow = tid >> 2;           // 0..63
    const int achk = (tid & 3) * 8;      // element offset within 32-wide k-slice
    int rs = m0 + arow; if (rs >= E) rs = E - 1;   // clamp tail (stores guarded)
    const int si = src[rs], ti = tgt[rs];
    const float* a0 = edge + (size_t)rs * D_DIM + achk;
    const float* a1 = node + (size_t)si * D_DIM + achk;
    const float* a2 = node + (size_t)ti * D_DIM + achk;
    const short* wrow = Wt + (size_t)tid * K_DIM;   // each thread stages one Wt row

    // ---- MFMA fragment coords ----
    const int lane = tid & 63;
    const int wv = tid >> 6;             // wave 0..3 -> N offset wv*64
    const int fr = lane & 15;            // A row / B col / C col index
    const int kq = (lane >> 4) * 8;      // k-quad offset (shorts)

    floatx4 acc[4][4] = {};

    float4 pA0, pA1, qA0, qA1;           // A ping-pong (2-deep prefetch)
    short8 rB0, rB1, rB2, rB3;           // B staging (1-deep)

#define LOADA(d0, d1, t) { \
    const int sg_ = (t) >> 3; \
    const float* ab_ = sg_ == 0 ? a0 : (sg_ == 1 ? a1 : a2); \
    const float4* ap_ = (const float4*)(ab_ + ((t) & 7) * BK); \
    d0 = ap_[0]; d1 = ap_[1]; }

#define LOADB(t) { \
    const short8* bp_ = (const short8*)(wrow + (t) * BK); \
    rB0 = bp_[0]; rB1 = bp_[1]; rB2 = bp_[2]; rB3 = bp_[3]; }

#define STORE(b, s0, s1) { \
    union { short8 v; short s[8]; } u_; \
    u_.s[0] = f2bf(s0.x); u_.s[1] = f2bf(s0.y); u_.s[2] = f2bf(s0.z); u_.s[3] = f2bf(s0.w); \
    u_.s[4] = f2bf(s1.x); u_.s[5] = f2bf(s1.y); u_.s[6] = f2bf(s1.z); u_.s[7] = f2bf(s1.w); \
    *(short8*)&As[b][arow][achk] = u_.v; \
    *(short8*)&Bs[b][tid][0]  = rB0; \
    *(short8*)&Bs[b][tid][8]  = rB1; \
    *(short8*)&Bs[b][tid][16] = rB2; \
    *(short8*)&Bs[b][tid][24] = rB3; }

#define COMPUTE(b) { \
    short8 bfr0 = *(const short8*)&Bs[b][wv * 64 +  0 + fr][kq]; \
    short8 bfr1 = *(const short8*)&Bs[b][wv * 64 + 16 + fr][kq]; \
    short8 bfr2 = *(const short8*)&Bs[b][wv * 64 + 32 + fr][kq]; \
    short8 bfr3 = *(const short8*)&Bs[b][wv * 64 + 48 + fr][kq]; \
    _Pragma("unroll") \
    for (int i_ = 0; i_ < 4; ++i_) { \
        short8 afr = *(const short8*)&As[b][i_ * 16 + fr][kq]; \
        acc[i_][0] = __builtin_amdgcn_mfma_f32_16x16x32_bf16(afr, bfr0, acc[i_][0], 0, 0, 0); \
        acc[i_][1] = __builtin_amdgcn_mfma_f32_16x16x32_bf16(afr, bfr1, acc[i_][1], 0, 0, 0); \
        acc[i_][2] = __builtin_amdgcn_mfma_f32_16x16x32_bf16(afr, bfr2, acc[i_][2], 0, 0, 0); \
        acc[i_][3] = __builtin_amdgcn_mfma_f32_16x16x32_bf16(afr, bfr3, acc[i_][3], 0, 0, 0); \
    } }

    // ---- prologue: stage step 0, launch step 1 ----
    LOADB(0);
    LOADA(qA0, qA1, 0);
    STORE(0, qA0, qA1);          // step 0 -> buf0 (cold vmcnt(0), once)
    LOADA(qA0, qA1, 1);          // step 1 in flight across the barrier
    __syncthreads();

    // ---- main loop: 2 k-steps per iteration, 1 barrier per k-step ----
#pragma unroll 1
    for (int t = 0; t < 22; t += 2) {
        // even: compute step t (buf0); write step t+1 (q + B); prefetch A(t+2)->p
        LOADB(t + 1);
        LOADA(pA0, pA1, t + 2);
        COMPUTE(0);
        STORE(1, qA0, qA1);
        __syncthreads();
        // odd: compute step t+1 (buf1); write step t+2 (p + B); prefetch A(t+3)->q
        LOADB(t + 2);
        LOADA(qA0, qA1, t + 3);
        COMPUTE(1);
        STORE(0, pA0, pA1);
        __syncthreads();
    }
    // t = 22: compute step 22 (buf0); write step 23 (q holds it)
    LOADB(23);
    COMPUTE(0);
    STORE(1, qA0, qA1);
    __syncthreads();
    // t = 23: final compute
    COMPUTE(1);

#undef LOADA
#undef LOADB
#undef STORE
#undef COMPUTE

    // ---- epilogue: bias + relu + guarded store ----
    float bv[4];
#pragma unroll
    for (int j = 0; j < 4; ++j) bv[j] = bias[wv * 64 + j * 16 + fr];
    const int rq = (lane >> 4) * 4;
#pragma unroll
    for (int i = 0; i < 4; ++i) {
        const int rbase = m0 + i * 16 + rq;
#pragma unroll
        for (int j = 0; j < 4; ++j) {
            const int c = wv * 64 + j * 16 + fr;
#pragma unroll
            for (int r = 0; r < 4; ++r) {
                const int rr = rbase + r;
                if (rr < E) {
                    float v = acc[i][j][r] + bv[j];
                    out[(size_t)rr * D_DIM + c] = v > 0.f ? v : 0.f;
                }
            }
        }
    }
}

extern "C" void kernel_launch(void* const* d_in, const int* in_sizes, int n_in,
                              void* d_out, int out_size, void* d_ws, size_t ws_size,
                              hipStream_t stream) {
    const float* edge = (const float*)d_in[0];
    const float* node = (const float*)d_in[1];
    const int*   srcI = (const int*)d_in[2];
    const int*   tgtI = (const int*)d_in[3];
    const float* W    = (const float*)d_in[4];
    const float* bias = (const float*)d_in[5];
    float* out = (float*)d_out;
    const int E = in_sizes[2];  // n_edges
    short* Wt = (short*)d_ws;   // needs K_DIM*D_DIM*2 = 393216 bytes

    dim3 tgrid(K_DIM / 32, D_DIM / 32);
    wt_kernel<<<tgrid, dim3(256), 0, stream>>>(W, Wt);

    dim3 ggrid((E + BM - 1) / BM);   // one block per 64 edge rows, full D in N
    edge_gemm<<<ggrid, dim3(256), 0, stream>>>(edge, node, srcI, tgtI, Wt, bias, out, E);
}

// Round 2
// 661.023 us; speedup vs baseline: 1.2308x; 1.2308x over previous
//
#include <hip/hip_runtime.h>
#include <hip/hip_bf16.h>

typedef __attribute__((ext_vector_type(8))) short short8;
typedef __attribute__((ext_vector_type(4))) float floatx4;

#define D_DIM 256
#define K_DIM 768
#define BM 64      // M rows per block
#define BK 32      // k-slice per step
#define PAD 40     // A LDS row stride in shorts (80B): conflict-free for our access pattern
#define NSTEP 24   // K_DIM / BK
#define BTILE 8192 // shorts per B k-tile (256 cols x 32 k = 16 KB)

// fp32 -> bf16 round-to-nearest-even (no NaN path needed: Gaussian inputs)
__device__ __forceinline__ short f2bf(float x) {
    union { float f; unsigned u; } a; a.f = x;
    unsigned r = a.u + 0x7fffu + ((a.u >> 16) & 1u);
    return (short)(r >> 16);
}

// XOR-swizzle involution within each 1KB window: byte bits[6:4] ^= bits[9:7].
// Chosen so the B fragment ds_read_b128 pattern (col*64 + (lane>>4)*16) is
// bank-conflict-free: per 8-lane cycle, the 8 lanes hit 8 distinct bank groups.
__device__ __forceinline__ unsigned swz(unsigned r) {
    return r ^ (((r >> 7) & 7u) << 4);
}

// W [K_DIM][D_DIM] fp32 -> Wt2: 24 contiguous 16KB k-tiles, tile t holding
// (col 0..255) x (kk 0..31) bf16 at PRE-SWIZZLED byte offsets, so that a linear
// global_load_lds copy + swizzled ds_read reproduce the logical layout (rule:
// swizzle both-sides-or-neither; source permutation == read permutation).
__global__ __launch_bounds__(256) void wt_kernel(const float* __restrict__ W,
                                                 short* __restrict__ Wt2) {
    const int k = blockIdx.x;      // 0..767
    const int n = threadIdx.x;     // 0..255 (output col)
    const int t = k >> 5, kk = k & 31;
    const unsigned r = (unsigned)n * 64u + (unsigned)kk * 2u;  // logical byte offset in tile
    Wt2[(size_t)t * BTILE + (swz(r) >> 1)] = f2bf(W[(size_t)k * D_DIM + n]);
}

// Fused gather + GEMM + bias + relu.
// C tile 64x256 per block (full D in N -> A panel read ONCE).
// 4 waves side by side in N, each wave 64x64 via 4x4 mfma_f32_16x16x32_bf16.
// B staged via global_load_lds (16B width) from the k-tiled pre-swizzled Wt2:
// fully coalesced 1KB-per-instr DMA, no VGPR round-trip. A reg-staged (fp32->bf16
// conversion requires it), 2-deep prefetch, single barrier per k-step.
__global__ __launch_bounds__(256, 3) void edge_gemm(
    const float* __restrict__ edge, const float* __restrict__ node,
    const int* __restrict__ src, const int* __restrict__ tgt,
    const short* __restrict__ Wt2, const float* __restrict__ bias,
    float* __restrict__ out, int E)
{
    __shared__ __align__(16) short As[2][BM][PAD];   // 10240 B
    __shared__ __align__(16) short Bs[2][BTILE];     // 32768 B (total 43 KB -> 3 blocks/CU)

    const int tid = threadIdx.x;
    const int m0 = blockIdx.x * BM;

    // ---- A staging coords: 4 threads per A row, 8 floats each ----
    const int arow = tid >> 2;           // 0..63
    const int achk = (tid & 3) * 8;      // float offset within 32-wide k-slice
    int rs = m0 + arow; if (rs >= E) rs = E - 1;   // clamp tail (stores guarded)
    const int si = src[rs], ti = tgt[rs];
    const float* a0 = edge + (size_t)rs * D_DIM + achk;
    const float* a1 = node + (size_t)si * D_DIM + achk;
    const float* a2 = node + (size_t)ti * D_DIM + achk;

    // ---- MFMA fragment coords ----
    const int lane = tid & 63;
    const int wv = tid >> 6;             // wave 0..3 -> N offset wv*64
    const int fr = lane & 15;            // A row / B col / C col index
    const int kq = (lane >> 4) * 8;      // k-quad offset (shorts)

    // ---- B DMA coords: wave wv stages bytes [wv*4096, wv*4096+4096) per tile ----
    const char* gb = (const char*)Wt2 + wv * 4096 + lane * 16;   // per-lane global src
    char* lb0 = (char*)&Bs[0][0] + wv * 4096;                    // wave-uniform LDS dst
    char* lb1 = (char*)&Bs[1][0] + wv * 4096;

    // ---- swizzled per-thread B read offsets (constant across k-steps) ----
    unsigned boff[4];
#pragma unroll
    for (int j = 0; j < 4; ++j) {
        unsigned col = (unsigned)(wv * 64 + j * 16 + fr);
        boff[j] = swz(col * 64u + (unsigned)(lane >> 4) * 16u);
    }

    floatx4 acc[4][4] = {};
    float4 pA0, pA1, qA0, qA1;           // A ping-pong (2-deep prefetch)

#define GLOADB(t, lb) { \
    const char* g_ = gb + (size_t)(t) * 16384; \
    __builtin_amdgcn_global_load_lds((const __attribute__((address_space(1))) unsigned*)(g_), \
        (__attribute__((address_space(3))) unsigned*)(lb), 16, 0, 0); \
    __builtin_amdgcn_global_load_lds((const __attribute__((address_space(1))) unsigned*)(g_ + 1024), \
        (__attribute__((address_space(3))) unsigned*)((lb) + 1024), 16, 0, 0); \
    __builtin_amdgcn_global_load_lds((const __attribute__((address_space(1))) unsigned*)(g_ + 2048), \
        (__attribute__((address_space(3))) unsigned*)((lb) + 2048), 16, 0, 0); \
    __builtin_amdgcn_global_load_lds((const __attribute__((address_space(1))) unsigned*)(g_ + 3072), \
        (__attribute__((address_space(3))) unsigned*)((lb) + 3072), 16, 0, 0); }

#define LOADA(d0, d1, t) { \
    const int sg_ = (t) >> 3; \
    const float* ab_ = sg_ == 0 ? a0 : (sg_ == 1 ? a1 : a2); \
    const float4* ap_ = (const float4*)(ab_ + ((t) & 7) * BK); \
    d0 = ap_[0]; d1 = ap_[1]; }

#define STOREA(b, s0, s1) { \
    union { short8 v; short s[8]; } u_; \
    u_.s[0] = f2bf(s0.x); u_.s[1] = f2bf(s0.y); u_.s[2] = f2bf(s0.z); u_.s[3] = f2bf(s0.w); \
    u_.s[4] = f2bf(s1.x); u_.s[5] = f2bf(s1.y); u_.s[6] = f2bf(s1.z); u_.s[7] = f2bf(s1.w); \
    *(short8*)&As[b][arow][achk] = u_.v; }

#define COMPUTE(b) { \
    const char* bb_ = (const char*)&Bs[b][0]; \
    short8 bfr0 = *(const short8*)(bb_ + boff[0]); \
    short8 bfr1 = *(const short8*)(bb_ + boff[1]); \
    short8 bfr2 = *(const short8*)(bb_ + boff[2]); \
    short8 bfr3 = *(const short8*)(bb_ + boff[3]); \
    _Pragma("unroll") \
    for (int i_ = 0; i_ < 4; ++i_) { \
        short8 afr = *(const short8*)&As[b][i_ * 16 + fr][kq]; \
        acc[i_][0] = __builtin_amdgcn_mfma_f32_16x16x32_bf16(afr, bfr0, acc[i_][0], 0, 0, 0); \
        acc[i_][1] = __builtin_amdgcn_mfma_f32_16x16x32_bf16(afr, bfr1, acc[i_][1], 0, 0, 0); \
        acc[i_][2] = __builtin_amdgcn_mfma_f32_16x16x32_bf16(afr, bfr2, acc[i_][2], 0, 0, 0); \
        acc[i_][3] = __builtin_amdgcn_mfma_f32_16x16x32_bf16(afr, bfr3, acc[i_][3], 0, 0, 0); \
    } }

    // ---- prologue: stage step 0, launch A(1) ----
    GLOADB(0, lb0);
    LOADA(qA0, qA1, 0);
    STOREA(0, qA0, qA1);
    LOADA(qA0, qA1, 1);
    __syncthreads();   // compiler-inserted vmcnt(0) drains the B DMA for buf0

    // ---- main loop: 2 k-steps per iteration, 1 barrier per k-step ----
#pragma unroll 1
    for (int t = 0; t < 22; t += 2) {
        // even: compute step t (buf0); DMA B(t+1)->buf1; write A(t+1); prefetch A(t+2)
        GLOADB(t + 1, lb1);
        LOADA(pA0, pA1, t + 2);
        COMPUTE(0);
        STOREA(1, qA0, qA1);
        __syncthreads();
        // odd: compute step t+1 (buf1); DMA B(t+2)->buf0; write A(t+2); prefetch A(t+3)
        GLOADB(t + 2, lb0);
        LOADA(qA0, qA1, t + 3);
        COMPUTE(1);
        STOREA(0, pA0, pA1);
        __syncthreads();
    }
    // t = 22: compute step 22 (buf0); DMA+write step 23
    GLOADB(23, lb1);
    COMPUTE(0);
    STOREA(1, qA0, qA1);
    __syncthreads();
    // t = 23: final compute
    COMPUTE(1);

#undef GLOADB
#undef LOADA
#undef STOREA
#undef COMPUTE

    // ---- epilogue: bias + relu + guarded store ----
    float bv[4];
#pragma unroll
    for (int j = 0; j < 4; ++j) bv[j] = bias[wv * 64 + j * 16 + fr];
    const int rq = (lane >> 4) * 4;
#pragma unroll
    for (int i = 0; i < 4; ++i) {
        const int rbase = m0 + i * 16 + rq;
#pragma unroll
        for (int j = 0; j < 4; ++j) {
            const int c = wv * 64 + j * 16 + fr;
#pragma unroll
            for (int r = 0; r < 4; ++r) {
                const int rr = rbase + r;
                if (rr < E) {
                    float v = acc[i][j][r] + bv[j];
                    out[(size_t)rr * D_DIM + c] = v > 0.f ? v : 0.f;
                }
            }
        }
    }
}

extern "C" void kernel_launch(void* const* d_in, const int* in_sizes, int n_in,
                              void* d_out, int out_size, void* d_ws, size_t ws_size,
                              hipStream_t stream) {
    const float* edge = (const float*)d_in[0];
    const float* node = (const float*)d_in[1];
    const int*   srcI = (const int*)d_in[2];
    const int*   tgtI = (const int*)d_in[3];
    const float* W    = (const float*)d_in[4];
    const float* bias = (const float*)d_in[5];
    float* out = (float*)d_out;
    const int E = in_sizes[2];  // n_edges
    short* Wt2 = (short*)d_ws;  // needs NSTEP*BTILE*2 = 393216 bytes

    wt_kernel<<<dim3(K_DIM), dim3(256), 0, stream>>>(W, Wt2);

    dim3 ggrid((E + BM - 1) / BM);   // one block per 64 edge rows, full D in N
    edge_gemm<<<ggrid, dim3(256), 0, stream>>>(edge, node, srcI, tgtI, Wt2, bias, out, E);
}